// Round 6
// baseline (563.233 us; speedup 1.0000x reference)
//
#include <hip/hip_runtime.h>

// CSTR gated-estimator trajectory cost — packed-FP32, 2 waves/SIMD.
//
// Law fitted to R1-R5: per-wave cost ~4.5 cyc per VALU instr at 1 wave/SIMD,
// independent of dependence structure (R4: two independent chains = exactly
// 2x time, zero overlap => per-wave issue cadence, not chain latency; R5:
// removing exp+rcp changed nothing => not transcendental latency).
// Levers: (1) halve instr count via v_pk_*_f32 (N=2 state is a natural f32x2;
// ext_vector_type(2) lets the backend select packed-math + op_sel),
// (2) 512-thread blocks -> 8 waves/CU -> 2 waves/SIMD so inter-wave
// interleave fills each wave's issue bubbles (cap: 2 cyc/instr execute).
// (3) restore 16-step register prefetch (R5 exposed ~60 cyc/step of mem).
//
// Math identical to R5 (passed, absmax 8.0): RK4 collapsed analytically,
// poly sigmoid d = 0.5 + u*P(u^2), u = clamp(phi/2, +-1.6).
// Packed quadratic form: u = X.aX + XH.aH + qc,
//   aX = GA X + 2GB XH + 0.5 M[0:2],  aH = GC XH + 0.5 M[2:4]
// with GA/GC symmetric (off-diag = scalar broadcast) from G = sym(L)/2.

#define T_STEPS 2048
#define BATCH   8192

typedef float f2 __attribute__((ext_vector_type(2)));
#define FMA2(a, b, c) __builtin_elementwise_fma((a), (b), (c))

__device__ __forceinline__ f2 sp(float s) { f2 r; r.x = s; r.y = s; return r; }
__device__ __forceinline__ f2 mk(float a, float b) { f2 r; r.x = a; r.y = b; return r; }

__global__ __launch_bounds__(512, 2) void cstr_kernel(
    const float* __restrict__ w,   // (B, 2, T)
    const float* __restrict__ K,   // (1, 2)
    const float* __restrict__ L,   // (4, 4)
    const float* __restrict__ M,   // (1, 4)
    const float* __restrict__ Mo,  // (1, 1)
    float* __restrict__ out)       // (B,)
{
    const int b = blockIdx.x * 512 + threadIdx.x;

    // ---- uniform scalars (same q-definitions as R5, verified) ----
    const float q11 = 0.5f * L[0];
    const float q12 = 0.5f * (L[1] + L[4]);
    const float q13 = 0.5f * (L[2] + L[8]);
    const float q14 = 0.5f * (L[3] + L[12]);
    const float q22 = 0.5f * L[5];
    const float q23 = 0.5f * (L[6] + L[9]);
    const float q24 = 0.5f * (L[7] + L[13]);
    const float q33 = 0.5f * L[10];
    const float q34 = 0.5f * (L[11] + L[14]);
    const float q44 = 0.5f * L[15];

    const f2 QAd = mk(q11, q22);      // GA diagonal
    const float qae = 0.5f * q12;     // GA off-diag (symmetric -> broadcast)
    const f2 QBd = mk(q13, q24);      // 2*GB diagonal
    const f2 QBe = mk(q14, q23);      // 2*GB anti-diagonal
    const f2 MX  = mk(0.5f * M[0], 0.5f * M[1]);
    const f2 QCd = mk(q33, q44);      // GC diagonal
    const float qce = 0.5f * q34;     // GC off-diag (symmetric -> broadcast)
    const f2 MH  = mk(0.5f * M[2], 0.5f * M[3]);
    const float qc = 0.5f * Mo[0];

    constexpr float Hs = 0.01f;
    constexpr float Ad = 1.0f - 2.0f * Hs;   // 0.98
    constexpr float RU = 0.1f / (Hs * Hs);   // R / H^2 = 1000
    // 0.5*tanh(u)/u interpolation (in s = u^2), |err| <= ~1.5e-4 on [-1.6,1.6]
    constexpr float PC0 = 0.5f;
    constexpr float PC1 = -0.16628205f;
    constexpr float PC2 = 0.06307510f;
    constexpr float PC3 = -0.01837280f;
    constexpr float PC4 = 0.00252805f;

    const f2 HK = mk(Hs * K[0], Hs * K[1]);              // Hs * K
    const f2 Cv = mk(0.5f * Hs * Hs, -Hs * Hs);          // RK4 constant offsets

    // ---- state ----
    f2 X  = mk(1.0f, 0.0f);
    f2 XH = X;
    float hkxh = HK.x;              // Hs * K.xh0
    f2 acc2 = sp(0.0f);             // packed sum (x1^2, x2^2)
    float accU = 0.0f;              // sum (Hs*K.x)^2
    float accD = 0.0f;              // sum delta

    auto step = [&](f2 wc, bool first, bool cost) {
        f2 Xs  = __builtin_shufflevector(X, X, 1, 0);
        f2 XHs = __builtin_shufflevector(XH, XH, 1, 0);
        // delta-independent
        f2 base = FMA2(sp(Ad), X, FMA2(sp(Hs), Xs, wc));
        f2 dxh  = X - XH;
        f2 hp   = HK * X;
        float hkx = hp.x + hp.y;                         // Hs * K.x
        float dk  = hkx - hkxh;
        if (cost) {
            acc2 = FMA2(X, X, acc2);
            accU = fmaf(hkx, hkx, accU);
        }
        // gate: u = phi/2 via packed quadratic form, then poly sigmoid
        float d;
        if (first) {
            d = 1.0f;
        } else {
            f2 aX = FMA2(QAd, X, FMA2(sp(qae), Xs, FMA2(QBd, XH, FMA2(QBe, XHs, MX))));
            f2 aH = FMA2(QCd, XH, FMA2(sp(qce), XHs, MH));
            f2 t  = X * aX;
            t     = FMA2(XH, aH, t);
            float u = (t.x + t.y) + qc;
            u = __builtin_amdgcn_fmed3f(u, -1.6f, 1.6f);
            float s  = u * u;
            float pp = fmaf(s, fmaf(s, fmaf(s, fmaf(s, PC4, PC3), PC2), PC1), PC0);
            d = fmaf(u, pp, 0.5f);
        }
        if (cost) accD += d;
        // short tail
        XH = FMA2(sp(d), dxh, XH);
        float hu = fmaf(d, dk, hkxh);   // Hs * K.xh_new
        hkxh = hu;
        X = base + sp(hu);
    };

    auto chunk = [&](const float4* b0, const float4* b1, bool first, bool lastchunk) {
        #pragma unroll
        for (int q = 0; q < 4; ++q) {
            float4 a = b0[q], c = b1[q];
            step(mk(a.x, c.x) + Cv, first && (q == 0), true);
            step(mk(a.y, c.y) + Cv, false, true);
            step(mk(a.z, c.z) + Cv, false, true);
            step(mk(a.w, c.w) + Cv, false, !(lastchunk && (q == 3)));
        }
    };

    // row streams: 512 float4 per row = 128 chunks of 16 steps
    const float4* r0 = reinterpret_cast<const float4*>(w + (size_t)b * (2 * T_STEPS));
    const float4* r1 = r0 + (T_STEPS / 4);

    float4 X0[4], X1[4], Y0[4], Y1[4];
    #pragma unroll
    for (int q = 0; q < 4; ++q) { X0[q] = r0[q];     X1[q] = r1[q]; }      // chunk 0
    #pragma unroll
    for (int q = 0; q < 4; ++q) { Y0[q] = r0[4 + q]; Y1[q] = r1[4 + q]; }  // chunk 1

    chunk(X0, X1, true, false);                        // chunk 0

    for (int i = 0; i < 63; ++i) {                     // chunks 1..126
        const float4* pa = r0 + (size_t)(2 + 2 * i) * 4;
        const float4* pb = r1 + (size_t)(2 + 2 * i) * 4;
        #pragma unroll
        for (int q = 0; q < 4; ++q) { X0[q] = pa[q]; X1[q] = pb[q]; }   // prefetch 2+2i
        chunk(Y0, Y1, false, false);                   // process 1+2i
        const float4* qa = r0 + (size_t)(3 + 2 * i) * 4;
        const float4* qb = r1 + (size_t)(3 + 2 * i) * 4;
        #pragma unroll
        for (int q = 0; q < 4; ++q) { Y0[q] = qa[q]; Y1[q] = qb[q]; }   // prefetch 3+2i
        chunk(X0, X1, false, false);                   // process 2+2i
    }
    chunk(Y0, Y1, false, true);                        // chunk 127 (t=T-1: no cost)

    // terminal cost 10*(x1^2+x2^2); unscale control cost
    f2 fin = FMA2(sp(10.0f) * X, X, acc2);
    out[b] = (fin.x + fin.y) + fmaf(RU, accU, accD);
}

extern "C" void kernel_launch(void* const* d_in, const int* in_sizes, int n_in,
                              void* d_out, int out_size, void* d_ws, size_t ws_size,
                              hipStream_t stream) {
    const float* w  = (const float*)d_in[0];
    const float* K  = (const float*)d_in[1];
    const float* L  = (const float*)d_in[2];
    const float* M  = (const float*)d_in[3];
    const float* Mo = (const float*)d_in[4];
    float* out = (float*)d_out;

    // 512-thread blocks: 8 waves/CU -> 2 waves per SIMD (16 blocks total)
    hipLaunchKernelGGL(cstr_kernel, dim3(BATCH / 512), dim3(512), 0, stream,
                       w, K, L, M, Mo, out);
}

// Round 7
// 348.308 us; speedup vs baseline: 1.6171x; 1.6171x over previous
//
#include <hip/hip_runtime.h>

// CSTR gated-estimator trajectory cost — hand-packed VOP3P, 1 thread/sample.
//
// Law fitted to R1-R6: wall = ~4.5 cyc per wave-instruction for non-DPP code,
// invariant to ILP (R4) and transcendentals (R5). R6 showed compiler-level f2
// vectors SCALARIZE (2x instr). So: force v_pk_*_f32 via inline asm (VOP3P,
// full-rate packed f32 on gfx950), swaps/broadcasts via op_sel (free), delta
// clamp via the VOP3P `clamp` modifier (fused, 0 extra instr). ~33 instr/step
// (vs ~42 in R1) and ~14-level loop-carried chain — wins under both candidate
// models (issue-cadence-bound OR chain-latency-bound).
//
// Math identical to R5 (passed): RK4 collapsed analytically, poly sigmoid
// delta = clamp(0.5 + u*P(u^2)), u = phi/2, Estrin form; carried dup-pair
// HKXH = dup(Hs*K.xh); all horizontal sums via op_sel cross-half adds.

#define T_STEPS 2048
#define BATCH   8192

typedef float f2 __attribute__((ext_vector_type(2)));

// ---- VOP3P packed-f32 helpers ----
__device__ __forceinline__ f2 pk_fma(f2 a, f2 b, f2 c) {
    f2 d; asm("v_pk_fma_f32 %0, %1, %2, %3" : "=v"(d) : "v"(a), "v"(b), "v"(c)); return d;
}
// src1 halves swapped: (a.x*b.y + c.x, a.y*b.x + c.y)
__device__ __forceinline__ f2 pk_fma_sw1(f2 a, f2 b, f2 c) {
    f2 d; asm("v_pk_fma_f32 %0, %1, %2, %3 op_sel:[0,1,0] op_sel_hi:[1,0,1]"
              : "=v"(d) : "v"(a), "v"(b), "v"(c)); return d;
}
// fma with result clamped to [0,1] (VOP3P clamp modifier)
__device__ __forceinline__ f2 pk_fma_clamp(f2 a, f2 b, f2 c) {
    f2 d; asm("v_pk_fma_f32 %0, %1, %2, %3 clamp" : "=v"(d) : "v"(a), "v"(b), "v"(c)); return d;
}
__device__ __forceinline__ f2 pk_add(f2 a, f2 b) {
    f2 d; asm("v_pk_add_f32 %0, %1, %2" : "=v"(d) : "v"(a), "v"(b)); return d;
}
// cross-half add: (a.x + b.y, a.y + b.x); with a==b -> dup(horizontal sum)
__device__ __forceinline__ f2 pk_add_sw1(f2 a, f2 b) {
    f2 d; asm("v_pk_add_f32 %0, %1, %2 op_sel:[0,1] op_sel_hi:[1,0]"
              : "=v"(d) : "v"(a), "v"(b)); return d;
}
__device__ __forceinline__ f2 pk_sub(f2 a, f2 b) {
    f2 d; asm("v_pk_add_f32 %0, %1, %2 neg_lo:[0,1] neg_hi:[0,1]"
              : "=v"(d) : "v"(a), "v"(b)); return d;
}
__device__ __forceinline__ f2 pk_mul(f2 a, f2 b) {
    f2 d; asm("v_pk_mul_f32 %0, %1, %2" : "=v"(d) : "v"(a), "v"(b)); return d;
}

__device__ __forceinline__ f2 mk2(float a, float b) { f2 r; r.x = a; r.y = b; return r; }

__global__ __launch_bounds__(64, 1) void cstr_kernel(
    const float* __restrict__ w,   // (B, 2, T)
    const float* __restrict__ K,   // (1, 2)
    const float* __restrict__ L,   // (4, 4)
    const float* __restrict__ M,   // (1, 4)
    const float* __restrict__ Mo,  // (1, 1)
    float* __restrict__ out)       // (B,)
{
    const int b = blockIdx.x * 64 + threadIdx.x;

    // ---- uniform scalars: halved symmetrized phi coefficients (u = phi/2) ----
    const float q11 = 0.5f * L[0];
    const float q12 = 0.5f * (L[1] + L[4]);
    const float q13 = 0.5f * (L[2] + L[8]);
    const float q14 = 0.5f * (L[3] + L[12]);
    const float q22 = 0.5f * L[5];
    const float q23 = 0.5f * (L[6] + L[9]);
    const float q24 = 0.5f * (L[7] + L[13]);
    const float q33 = 0.5f * L[10];
    const float q34 = 0.5f * (L[11] + L[14]);
    const float q44 = 0.5f * L[15];

    constexpr float Hs = 0.01f;
    constexpr float Ad = 1.0f - 2.0f * Hs;   // 0.98
    constexpr float C1 = 0.5f * Hs * Hs;
    constexpr float C2 = -Hs * Hs;
    constexpr float RU = 0.1f / (Hs * Hs);   // R / H^2
    // 0.5*tanh(u)/u fit in s = u^2 (Estrin), |err|<=1.5e-4 on |u|<=1.6
    constexpr float PC0 = 0.5f;
    constexpr float PC1 = -0.16628205f;
    constexpr float PC2 = 0.06307510f;
    constexpr float PC3 = -0.01837280f;
    constexpr float PC4 = 0.00252805f;

    const float hk1 = Hs * K[0], hk2 = Hs * K[1];

    // ---- loop-invariant constant pairs ----
    const f2 CvP  = mk2(C1, C2);
    const f2 HS2  = mk2(Hs, Hs);
    const f2 AD2  = mk2(Ad, Ad);
    const f2 HK2  = mk2(hk1, hk2);
    const f2 QA1  = mk2(q11, q22);
    const f2 QA2  = mk2(q12, 0.0f);
    const f2 QA3  = mk2(q13, q24);
    const f2 QA4  = mk2(q14, q23);
    const f2 M12  = mk2(0.5f * M[0], 0.5f * M[1]);
    const f2 QB1  = mk2(q33, q44);
    const f2 QB2  = mk2(q34, 0.0f);
    const f2 M34  = mk2(0.5f * M[2], 0.5f * M[3]);
    const f2 QC2  = mk2(0.5f * Mo[0], 0.0f);
    const f2 H2   = mk2(0.5f, 0.5f);
    const f2 PC0P = mk2(PC0, PC0);
    const f2 PC1P = mk2(PC1, PC1);
    const f2 PC2P = mk2(PC2, PC2);
    const f2 PC3P = mk2(PC3, PC3);
    const f2 PC4P = mk2(PC4, PC4);

    // ---- streams: row1 = w[b][0][:], row2 = w[b][1][:] ----
    const float4* r0 = reinterpret_cast<const float4*>(w + (size_t)b * (2 * T_STEPS));
    const float4* r1 = r0 + (T_STEPS / 4);

    float4 X0[4], X1[4], Y0[4], Y1[4];
    #pragma unroll
    for (int q = 0; q < 4; ++q) { X0[q] = r0[q];     X1[q] = r1[q]; }      // chunk 0
    #pragma unroll
    for (int q = 0; q < 4; ++q) { Y0[q] = r0[4 + q]; Y1[q] = r1[4 + q]; }  // chunk 1

    // ---- peel step 0 (delta forced to 1; x0 = xh0 = (1,0)) ----
    // cost(t=0): x.x=1 -> accO=1; us=K.x0=K1 -> accU=(hk1)^2 (Hs^2-scaled); accD=1
    // x1 = Ad + Hs*0 + hu + C1 + w1[0], hu = hk1 (dk=0)
    f2 X  = mk2(Ad + X0[0].x + C1 + hk1, Hs + X1[0].x + C2 + hk1);
    f2 XH = mk2(1.0f, 0.0f);
    f2 HKXH = mk2(hk1, hk1);          // dup(Hs*K.xh)
    f2 ACC2 = mk2(1.0f, 0.0f);        // packed sum (x1^2, x2^2)
    float accU = hk1 * hk1;           // sum (Hs*K.x)^2
    float accD = 1.0f;                // sum delta

    // ---- the packed step (t >= 1) ----
    auto dostep = [&](float w1, float w2, bool ct) {
        f2 Wp = mk2(w1, w2);
        f2 WC = pk_add(Wp, CvP);                    // w + RK4 const offsets
        f2 T  = pk_fma_sw1(HS2, X, WC);             // (Hs*x2+w1c, Hs*x1+w2c)
        f2 V  = pk_fma(AD2, X, T);                  // + Ad*x
        V = pk_add(V, HKXH);                        // + hkxh  (V = base + hkxh)
        f2 E  = pk_sub(X, XH);                      // x - xh
        f2 HP = pk_mul(HK2, X);                     // (hk1*x1, hk2*x2)
        f2 HKX2 = pk_add_sw1(HP, HP);               // dup(Hs*K.x)
        f2 DK2  = pk_sub(HKX2, HKXH);               // dup(dk)
        if (ct) {
            ACC2 = pk_fma(X, X, ACC2);
            accU = fmaf(HKX2.x, HKX2.x, accU);
        }
        // phi one-sided rows, packed
        f2 A = pk_fma_sw1(QA4, XH, M12);            // (q14*xh2+m1, q23*xh1+m2)
        A = pk_fma(QA3, XH, A);                     // +(q13*xh1, q24*xh2)
        A = pk_fma_sw1(QA2, X, A);                  // +(q12*x2, 0)
        A = pk_fma(QA1, X, A);                      // +(q11*x1, q22*x2)
        f2 Bp = pk_fma_sw1(QB2, XH, M34);           // (q34*xh2+m3, m4)
        Bp = pk_fma(QB1, XH, Bp);                   // +(q33*xh1, q44*xh2)
        f2 U = pk_fma(XH, Bp, QC2);
        U = pk_fma(X, A, U);
        f2 Us = pk_add_sw1(U, U);                   // dup(u = phi/2)
        // poly sigmoid, packed Estrin, clamp fused into final fma
        f2 S  = pk_mul(Us, Us);
        f2 S2 = pk_mul(S, S);
        f2 PA = pk_fma(S, PC1P, PC0P);
        f2 PB = pk_fma(S, PC3P, PC2P);
        f2 PCt = pk_fma(S2, PC4P, PB);
        f2 PP = pk_fma(S2, PCt, PA);
        f2 D2 = pk_fma_clamp(Us, PP, H2);           // dup(delta), clamped [0,1]
        if (ct) accD += D2.x;
        // updates
        f2 SDK = pk_mul(D2, DK2);                   // dup(delta*dk)
        XH = pk_fma(D2, E, XH);
        X  = pk_add(V, SDK);                        // base + hkxh + delta*dk
        HKXH = pk_add(HKXH, SDK);                   // dup(hu) carried
    };

    auto chunk = [&](const float4* b0, const float4* b1, bool skip0, bool last) {
        #pragma unroll
        for (int q = 0; q < 4; ++q) {
            float4 a = b0[q], c = b1[q];
            if (!(skip0 && q == 0)) dostep(a.x, c.x, true);
            dostep(a.y, c.y, true);
            dostep(a.z, c.z, true);
            dostep(a.w, c.w, !(last && (q == 3)));   // t=T-1: no stage cost
        }
    };

    chunk(X0, X1, true, false);                        // chunk 0 (steps 1..15)

    for (int i = 0; i < 63; ++i) {                     // chunks 1..126
        const float4* pa = r0 + (size_t)(2 + 2 * i) * 4;
        const float4* pb = r1 + (size_t)(2 + 2 * i) * 4;
        #pragma unroll
        for (int q = 0; q < 4; ++q) { X0[q] = pa[q]; X1[q] = pb[q]; }   // prefetch 2+2i
        chunk(Y0, Y1, false, false);                   // process 1+2i
        const float4* qa = r0 + (size_t)(3 + 2 * i) * 4;
        const float4* qb = r1 + (size_t)(3 + 2 * i) * 4;
        #pragma unroll
        for (int q = 0; q < 4; ++q) { Y0[q] = qa[q]; Y1[q] = qb[q]; }   // prefetch 3+2i
        chunk(X0, X1, false, false);                   // process 2+2i
    }
    chunk(Y0, Y1, false, true);                        // chunk 127 (t=2047: no cost)

    // terminal cost 10*(x1^2+x2^2); unscale control cost
    float J = (ACC2.x + ACC2.y) + fmaf(RU, accU, accD);
    out[b] = fmaf(10.0f, fmaf(X.x, X.x, X.y * X.y), J);
}

extern "C" void kernel_launch(void* const* d_in, const int* in_sizes, int n_in,
                              void* d_out, int out_size, void* d_ws, size_t ws_size,
                              hipStream_t stream) {
    const float* w  = (const float*)d_in[0];
    const float* K  = (const float*)d_in[1];
    const float* L  = (const float*)d_in[2];
    const float* M  = (const float*)d_in[3];
    const float* Mo = (const float*)d_in[4];
    float* out = (float*)d_out;

    hipLaunchKernelGGL(cstr_kernel, dim3(BATCH / 64), dim3(64), 0, stream,
                       w, K, L, M, Mo, out);
}